// Round 2
// baseline (386.866 us; speedup 1.0000x reference)
//
#include <hip/hip_runtime.h>
#include <hip/hip_bf16.h>
#include <stdint.h>

typedef __bf16 bf16x8 __attribute__((ext_vector_type(8)));
typedef float  f32x4  __attribute__((ext_vector_type(4)));
typedef unsigned short ushortx8 __attribute__((ext_vector_type(8)));

#define LDS_B(p) ((__attribute__((address_space(3))) void*)(p))
#define GLB_B(p) ((const __attribute__((address_space(1))) void*)(p))

__device__ __forceinline__ unsigned short f2bf_rn(float f) {
  union { float f; uint32_t u; } v; v.f = f;
  uint32_t u = v.u;
  u += 0x7FFFu + ((u >> 16) & 1u);
  return (unsigned short)(u >> 16);
}

// ---------------- prep kernels (memory-bound, 8 elems/thread) ----------------

__global__ void cvt_f32_to_bf16(const float* __restrict__ in,
                                unsigned short* __restrict__ out, int n) {
  int i = (blockIdx.x * 256 + threadIdx.x) * 8;
  if (i >= n) return;
  const float4 f0 = *(const float4*)(in + i);
  const float4 f1 = *(const float4*)(in + i + 4);
  ushortx8 o;
  o[0] = f2bf_rn(f0.x); o[1] = f2bf_rn(f0.y);
  o[2] = f2bf_rn(f0.z); o[3] = f2bf_rn(f0.w);
  o[4] = f2bf_rn(f1.x); o[5] = f2bf_rn(f1.y);
  o[6] = f2bf_rn(f1.z); o[7] = f2bf_rn(f1.w);
  *(ushortx8*)(out + i) = o;
}

__global__ void binarize_to_bf16(const float* __restrict__ in,
                                 unsigned short* __restrict__ out, int n) {
  int i = (blockIdx.x * 256 + threadIdx.x) * 8;
  if (i >= n) return;
  const float4 f0 = *(const float4*)(in + i);
  const float4 f1 = *(const float4*)(in + i + 4);
  // bf16 +1.0 = 0x3F80, -1.0 = 0xBF80.  Use >=0 compare so -0.0f -> +1 (IEEE: -0.0 >= 0).
  ushortx8 o;
  o[0] = f0.x >= 0.f ? 0x3F80 : 0xBF80;
  o[1] = f0.y >= 0.f ? 0x3F80 : 0xBF80;
  o[2] = f0.z >= 0.f ? 0x3F80 : 0xBF80;
  o[3] = f0.w >= 0.f ? 0x3F80 : 0xBF80;
  o[4] = f1.x >= 0.f ? 0x3F80 : 0xBF80;
  o[5] = f1.y >= 0.f ? 0x3F80 : 0xBF80;
  o[6] = f1.z >= 0.f ? 0x3F80 : 0xBF80;
  o[7] = f1.w >= 0.f ? 0x3F80 : 0xBF80;
  *(ushortx8*)(out + i) = o;
}

// ---------------- GEMM: C[m][n] = sum_k A[m][k]*B[n][k]  (both K-contiguous) ----------------
// 128x128 tile, BK=32, 4 waves (2x2), each wave 64x64 via 4x4 mfma_f32_16x16x32_bf16.
// MODE 0: +bias, ReLU, bf16 out.  MODE 1: +bias, f32 out.

template <int MODE>
__global__ __launch_bounds__(256, 2)
void gemm_bt_128(const unsigned short* __restrict__ A,   // M x K bf16 bits
                 const unsigned short* __restrict__ B,   // N x K bf16 bits
                 const float* __restrict__ bias,         // N
                 void* __restrict__ C,
                 int M, int N, int K)
{
  __shared__ unsigned short As[2][128][32];
  __shared__ unsigned short Bs[2][128][32];

  const int tid  = threadIdx.x;
  const int wid  = tid >> 6;
  const int lane = tid & 63;

  const int row0 = blockIdx.x * 128;
  const int col0 = blockIdx.y * 128;

  // staging map: thread t covers LDS bytes [t*16, t*16+16) of a 64-row x 32-col chunk
  const int srow = tid >> 2;          // 0..63
  const int scol = (tid & 3) << 3;    // 0,8,16,24 (bf16 elems)

  const size_t aBase = (size_t)(row0 + srow) * K + scol;
  const size_t bBase = (size_t)(col0 + srow) * K + scol;
  const int ldsWaveOff = wid << 10;   // bytes: each wave writes 1KB per issue

  // fragment indices (16x16x32: lane holds row/col = lane&15, k = (lane>>4)*8 + j)
  const int fr = lane & 15;
  const int fq = lane >> 4;
  const int wr = (wid >> 1) * 64;
  const int wc = (wid & 1) * 64;

  f32x4 acc[4][4] = {};

  const int nt = K >> 5;   // K/32

  auto stage = [&](int buf, int t) {
    const size_t k0 = (size_t)t << 5;
    const unsigned short* a0 = A + aBase + k0;
    const unsigned short* a1 = a0 + (size_t)64 * K;
    const unsigned short* b0 = B + bBase + k0;
    const unsigned short* b1 = b0 + (size_t)64 * K;
    char* aL = (char*)&As[buf][0][0] + ldsWaveOff;
    char* bL = (char*)&Bs[buf][0][0] + ldsWaveOff;
    __builtin_amdgcn_global_load_lds(GLB_B(a0), LDS_B(aL),        16, 0, 0);
    __builtin_amdgcn_global_load_lds(GLB_B(a1), LDS_B(aL + 4096), 16, 0, 0);
    __builtin_amdgcn_global_load_lds(GLB_B(b0), LDS_B(bL),        16, 0, 0);
    __builtin_amdgcn_global_load_lds(GLB_B(b1), LDS_B(bL + 4096), 16, 0, 0);
  };

  auto compute = [&](int buf) {
    bf16x8 af[4], bq[4];
#pragma unroll
    for (int mi = 0; mi < 4; ++mi)
      af[mi] = *(const bf16x8*)&As[buf][wr + mi * 16 + fr][fq << 3];
#pragma unroll
    for (int ni = 0; ni < 4; ++ni)
      bq[ni] = *(const bf16x8*)&Bs[buf][wc + ni * 16 + fr][fq << 3];
#pragma unroll
    for (int mi = 0; mi < 4; ++mi)
#pragma unroll
      for (int ni = 0; ni < 4; ++ni)
        acc[mi][ni] = __builtin_amdgcn_mfma_f32_16x16x32_bf16(
            af[mi], bq[ni], acc[mi][ni], 0, 0, 0);
  };

  stage(0, 0);
  __syncthreads();   // drains vmcnt(0): buf0 staged

  int cur = 0;
  for (int t = 0; t < nt - 1; ++t) {
    stage(cur ^ 1, t + 1);   // prefetch next K-tile
    compute(cur);
    __syncthreads();         // drains vmcnt+lgkm: next buf ready, cur reads done
    cur ^= 1;
  }
  compute(cur);

  // epilogue: C/D layout col = lane&15, row = (lane>>4)*4 + j  [m89/m91]
  float bv[4];
#pragma unroll
  for (int ni = 0; ni < 4; ++ni)
    bv[ni] = bias[col0 + wc + ni * 16 + fr];

#pragma unroll
  for (int mi = 0; mi < 4; ++mi) {
#pragma unroll
    for (int ni = 0; ni < 4; ++ni) {
      const int c = col0 + wc + ni * 16 + fr;
#pragma unroll
      for (int j = 0; j < 4; ++j) {
        const int r = row0 + wr + mi * 16 + fq * 4 + j;
        float v = acc[mi][ni][j] + bv[ni];
        if (MODE == 0) {
          v = v > 0.f ? v : 0.f;
          ((unsigned short*)C)[(size_t)r * N + c] = f2bf_rn(v);
        } else {
          ((float*)C)[(size_t)r * N + c] = v;
        }
      }
    }
  }
}

// ---------------- launcher ----------------

extern "C" void kernel_launch(void* const* d_in, const int* in_sizes, int n_in,
                              void* d_out, int out_size, void* d_ws, size_t ws_size,
                              hipStream_t stream) {
  const float* x  = (const float*)d_in[0];
  const float* w1 = (const float*)d_in[1];
  const float* b1 = (const float*)d_in[2];
  const float* w2 = (const float*)d_in[3];
  const float* b2 = (const float*)d_in[4];
  float* out = (float*)d_out;

  constexpr int M = 4096, K = 4096, H = 4096, O = 1024;

  char* ws = (char*)d_ws;
  unsigned short* xb  = (unsigned short*)(ws);                         // 32 MB
  unsigned short* w1b = (unsigned short*)(ws + (size_t)33554432);      // 32 MB
  unsigned short* w2b = (unsigned short*)(ws + (size_t)67108864);      //  8 MB
  unsigned short* hb  = (unsigned short*)(ws + (size_t)75497472);      // 32 MB

  cvt_f32_to_bf16 <<<(M * K / 8 + 255) / 256, 256, 0, stream>>>(x,  xb,  M * K);
  binarize_to_bf16<<<(H * K / 8 + 255) / 256, 256, 0, stream>>>(w1, w1b, H * K);
  binarize_to_bf16<<<(O * H / 8 + 255) / 256, 256, 0, stream>>>(w2, w2b, O * H);

  gemm_bt_128<0><<<dim3(M / 128, H / 128), 256, 0, stream>>>(xb, w1b, b1, (void*)hb,  M, H, K);
  gemm_bt_128<1><<<dim3(M / 128, O / 128), 256, 0, stream>>>(hb, w2b, b2, (void*)out, M, O, H);
}

// Round 3
// 365.076 us; speedup vs baseline: 1.0597x; 1.0597x over previous
//
#include <hip/hip_runtime.h>
#include <hip/hip_bf16.h>
#include <stdint.h>

typedef __bf16 bf16x8 __attribute__((ext_vector_type(8)));
typedef float  f32x4  __attribute__((ext_vector_type(4)));
typedef unsigned short ushortx8 __attribute__((ext_vector_type(8)));

#define LDS_B(p) ((__attribute__((address_space(3))) void*)(p))
#define GLB_B(p) ((const __attribute__((address_space(1))) void*)(p))

__device__ __forceinline__ unsigned short f2bf_rn(float f) {
  union { float f; uint32_t u; } v; v.f = f;
  uint32_t u = v.u;
  u += 0x7FFFu + ((u >> 16) & 1u);
  return (unsigned short)(u >> 16);
}

// ---------------- prep kernels (memory-bound, 8 elems/thread) ----------------

__global__ void cvt_f32_to_bf16(const float* __restrict__ in,
                                unsigned short* __restrict__ out, int n) {
  int i = (blockIdx.x * 256 + threadIdx.x) * 8;
  if (i >= n) return;
  const float4 f0 = *(const float4*)(in + i);
  const float4 f1 = *(const float4*)(in + i + 4);
  ushortx8 o;
  o[0] = f2bf_rn(f0.x); o[1] = f2bf_rn(f0.y);
  o[2] = f2bf_rn(f0.z); o[3] = f2bf_rn(f0.w);
  o[4] = f2bf_rn(f1.x); o[5] = f2bf_rn(f1.y);
  o[6] = f2bf_rn(f1.z); o[7] = f2bf_rn(f1.w);
  *(ushortx8*)(out + i) = o;
}

__global__ void binarize_to_bf16(const float* __restrict__ in,
                                 unsigned short* __restrict__ out, int n) {
  int i = (blockIdx.x * 256 + threadIdx.x) * 8;
  if (i >= n) return;
  const float4 f0 = *(const float4*)(in + i);
  const float4 f1 = *(const float4*)(in + i + 4);
  // bf16 +1.0 = 0x3F80, -1.0 = 0xBF80.  >=0 compare so -0.0f -> +1.
  ushortx8 o;
  o[0] = f0.x >= 0.f ? 0x3F80 : 0xBF80;
  o[1] = f0.y >= 0.f ? 0x3F80 : 0xBF80;
  o[2] = f0.z >= 0.f ? 0x3F80 : 0xBF80;
  o[3] = f0.w >= 0.f ? 0x3F80 : 0xBF80;
  o[4] = f1.x >= 0.f ? 0x3F80 : 0xBF80;
  o[5] = f1.y >= 0.f ? 0x3F80 : 0xBF80;
  o[6] = f1.z >= 0.f ? 0x3F80 : 0xBF80;
  o[7] = f1.w >= 0.f ? 0x3F80 : 0xBF80;
  *(ushortx8*)(out + i) = o;
}

// ---------------- GEMM core: C[m][n] = sum_k A[m][k]*B[n][k] ----------------
// 128x128 tile, BK=32, 4 waves (2x2), each wave 64x64 via 4x4 mfma_f32_16x16x32_bf16.
// MODE 0: +bias, ReLU, bf16 out (full K).
// MODE 2: split-K partial, f32 out to P + blockIdx.z*M*N, no bias.

template <int MODE>
__global__ __launch_bounds__(256, 2)
void gemm_bt_128(const unsigned short* __restrict__ A,   // M x K bf16 bits
                 const unsigned short* __restrict__ B,   // N x K bf16 bits
                 const float* __restrict__ bias,         // N (MODE 0 only)
                 void* __restrict__ C,
                 int M, int N, int K, int KS)            // KS: K-span per z-split (MODE 2)
{
  __shared__ unsigned short As[2][128][32];
  __shared__ unsigned short Bs[2][128][32];

  const int tid  = threadIdx.x;
  const int wid  = tid >> 6;
  const int lane = tid & 63;

  const int row0 = blockIdx.x * 128;
  const int col0 = blockIdx.y * 128;
  const int kOff = (MODE == 2) ? blockIdx.z * KS : 0;
  const int kLen = (MODE == 2) ? KS : K;

  // staging map: thread t covers LDS bytes [t*16, t*16+16) of a 64-row x 32-col chunk
  const int srow = tid >> 2;          // 0..63
  const int scol = (tid & 3) << 3;    // 0,8,16,24 (bf16 elems)

  const size_t aBase = (size_t)(row0 + srow) * K + scol + kOff;
  const size_t bBase = (size_t)(col0 + srow) * K + scol + kOff;
  const int ldsWaveOff = wid << 10;   // bytes

  const int fr = lane & 15;
  const int fq = lane >> 4;
  const int wr = (wid >> 1) * 64;
  const int wc = (wid & 1) * 64;

  f32x4 acc[4][4] = {};

  const int nt = kLen >> 5;   // per-block K-iterations

  auto stage = [&](int buf, int t) {
    const size_t k0 = (size_t)t << 5;
    const unsigned short* a0 = A + aBase + k0;
    const unsigned short* a1 = a0 + (size_t)64 * K;
    const unsigned short* b0 = B + bBase + k0;
    const unsigned short* b1 = b0 + (size_t)64 * K;
    char* aL = (char*)&As[buf][0][0] + ldsWaveOff;
    char* bL = (char*)&Bs[buf][0][0] + ldsWaveOff;
    __builtin_amdgcn_global_load_lds(GLB_B(a0), LDS_B(aL),        16, 0, 0);
    __builtin_amdgcn_global_load_lds(GLB_B(a1), LDS_B(aL + 4096), 16, 0, 0);
    __builtin_amdgcn_global_load_lds(GLB_B(b0), LDS_B(bL),        16, 0, 0);
    __builtin_amdgcn_global_load_lds(GLB_B(b1), LDS_B(bL + 4096), 16, 0, 0);
  };

  auto compute = [&](int buf) {
    bf16x8 af[4], bq[4];
#pragma unroll
    for (int mi = 0; mi < 4; ++mi)
      af[mi] = *(const bf16x8*)&As[buf][wr + mi * 16 + fr][fq << 3];
#pragma unroll
    for (int ni = 0; ni < 4; ++ni)
      bq[ni] = *(const bf16x8*)&Bs[buf][wc + ni * 16 + fr][fq << 3];
#pragma unroll
    for (int mi = 0; mi < 4; ++mi)
#pragma unroll
      for (int ni = 0; ni < 4; ++ni)
        acc[mi][ni] = __builtin_amdgcn_mfma_f32_16x16x32_bf16(
            af[mi], bq[ni], acc[mi][ni], 0, 0, 0);
  };

  stage(0, 0);
  __syncthreads();

  int cur = 0;
  for (int t = 0; t < nt - 1; ++t) {
    stage(cur ^ 1, t + 1);
    compute(cur);
    __syncthreads();
    cur ^= 1;
  }
  compute(cur);

  // epilogue: C/D layout col = lane&15, row = (lane>>4)*4 + j  [m89/m91]
  float bv[4];
  if (MODE == 0) {
#pragma unroll
    for (int ni = 0; ni < 4; ++ni)
      bv[ni] = bias[col0 + wc + ni * 16 + fr];
  }

  float* Cz = (MODE == 2)
      ? ((float*)C + (size_t)blockIdx.z * M * N)
      : (float*)C;

#pragma unroll
  for (int mi = 0; mi < 4; ++mi) {
#pragma unroll
    for (int ni = 0; ni < 4; ++ni) {
      const int c = col0 + wc + ni * 16 + fr;
#pragma unroll
      for (int j = 0; j < 4; ++j) {
        const int r = row0 + wr + mi * 16 + fq * 4 + j;
        if (MODE == 0) {
          float v = acc[mi][ni][j] + bv[ni];
          v = v > 0.f ? v : 0.f;
          ((unsigned short*)C)[(size_t)r * N + c] = f2bf_rn(v);
        } else {
          Cz[(size_t)r * N + c] = acc[mi][ni][j];
        }
      }
    }
  }
}

// ---------------- split-K reduction: out = sum_s P[s] + bias ----------------
// N must be a power of two (N=1024 here). 4 floats/thread.

__global__ void reduce4_bias(const float4* __restrict__ P,
                             const float* __restrict__ bias,
                             float4* __restrict__ out,
                             int MN4, int n4mask) {
  int j = blockIdx.x * 256 + threadIdx.x;
  if (j >= MN4) return;
  float4 a = P[j];
  float4 b = P[j + MN4];
  float4 c = P[j + 2 * MN4];
  float4 d = P[j + 3 * MN4];
  float4 bv = *(const float4*)(bias + ((j & n4mask) << 2));
  float4 o;
  o.x = (a.x + b.x) + (c.x + d.x) + bv.x;
  o.y = (a.y + b.y) + (c.y + d.y) + bv.y;
  o.z = (a.z + b.z) + (c.z + d.z) + bv.z;
  o.w = (a.w + b.w) + (c.w + d.w) + bv.w;
  out[j] = o;
}

// ---------------- launcher ----------------

extern "C" void kernel_launch(void* const* d_in, const int* in_sizes, int n_in,
                              void* d_out, int out_size, void* d_ws, size_t ws_size,
                              hipStream_t stream) {
  const float* x  = (const float*)d_in[0];
  const float* w1 = (const float*)d_in[1];
  const float* b1 = (const float*)d_in[2];
  const float* w2 = (const float*)d_in[3];
  const float* b2 = (const float*)d_in[4];
  float* out = (float*)d_out;

  constexpr int M = 4096, K = 4096, H = 4096, O = 1024;
  constexpr int SPLITS = 4;

  char* ws = (char*)d_ws;
  // layout: [0,64MB) split-K partials (reused region — xb/w1b live only until GEMM1)
  //         xb @0 (32MB), w1b @32MB (32MB), w2b @64MB (8MB), hb @72MB (32MB)
  unsigned short* xb   = (unsigned short*)(ws);
  unsigned short* w1b  = (unsigned short*)(ws + (size_t)33554432);
  unsigned short* w2b  = (unsigned short*)(ws + (size_t)67108864);
  unsigned short* hb   = (unsigned short*)(ws + (size_t)75497472);
  float*          part = (float*)(ws);   // 4 x 16MB f32 partials, overlaps xb/w1b

  cvt_f32_to_bf16 <<<(M * K / 8 + 255) / 256, 256, 0, stream>>>(x,  xb,  M * K);
  binarize_to_bf16<<<(H * K / 8 + 255) / 256, 256, 0, stream>>>(w1, w1b, H * K);
  binarize_to_bf16<<<(O * H / 8 + 255) / 256, 256, 0, stream>>>(w2, w2b, O * H);

  // layer 1: h = relu(x·sign(w1)^T + b1), bf16 out
  gemm_bt_128<0><<<dim3(M / 128, H / 128), 256, 0, stream>>>(
      xb, w1b, b1, (void*)hb, M, H, K, 0);

  // layer 2: split-K=4 partials (1024 blocks -> ~4/CU), then reduce+bias
  gemm_bt_128<2><<<dim3(M / 128, O / 128, SPLITS), 256, 0, stream>>>(
      hb, w2b, nullptr, (void*)part, M, O, H, H / SPLITS);

  constexpr int MN4 = M * O / 4;
  reduce4_bias<<<(MN4 + 255) / 256, 256, 0, stream>>>(
      (const float4*)part, b2, (float4*)out, MN4, O / 4 - 1);
}

// Round 4
// 344.884 us; speedup vs baseline: 1.1217x; 1.0585x over previous
//
#include <hip/hip_runtime.h>
#include <hip/hip_bf16.h>
#include <stdint.h>

typedef __bf16 bf16x8 __attribute__((ext_vector_type(8)));
typedef float  f32x4  __attribute__((ext_vector_type(4)));
typedef unsigned short ushortx8 __attribute__((ext_vector_type(8)));

#define LDS_B(p) ((__attribute__((address_space(3))) void*)(p))
#define GLB_B(p) ((const __attribute__((address_space(1))) void*)(p))

__device__ __forceinline__ unsigned short f2bf_rn(float f) {
  union { float f; uint32_t u; } v; v.f = f;
  uint32_t u = v.u;
  u += 0x7FFFu + ((u >> 16) & 1u);
  return (unsigned short)(u >> 16);
}

// ---------------- prep kernels (unchanged) ----------------

__global__ void cvt_f32_to_bf16(const float* __restrict__ in,
                                unsigned short* __restrict__ out, int n) {
  int i = (blockIdx.x * 256 + threadIdx.x) * 8;
  if (i >= n) return;
  const float4 f0 = *(const float4*)(in + i);
  const float4 f1 = *(const float4*)(in + i + 4);
  ushortx8 o;
  o[0] = f2bf_rn(f0.x); o[1] = f2bf_rn(f0.y);
  o[2] = f2bf_rn(f0.z); o[3] = f2bf_rn(f0.w);
  o[4] = f2bf_rn(f1.x); o[5] = f2bf_rn(f1.y);
  o[6] = f2bf_rn(f1.z); o[7] = f2bf_rn(f1.w);
  *(ushortx8*)(out + i) = o;
}

__global__ void binarize_to_bf16(const float* __restrict__ in,
                                 unsigned short* __restrict__ out, int n) {
  int i = (blockIdx.x * 256 + threadIdx.x) * 8;
  if (i >= n) return;
  const float4 f0 = *(const float4*)(in + i);
  const float4 f1 = *(const float4*)(in + i + 4);
  ushortx8 o;
  o[0] = f0.x >= 0.f ? 0x3F80 : 0xBF80;
  o[1] = f0.y >= 0.f ? 0x3F80 : 0xBF80;
  o[2] = f0.z >= 0.f ? 0x3F80 : 0xBF80;
  o[3] = f0.w >= 0.f ? 0x3F80 : 0xBF80;
  o[4] = f1.x >= 0.f ? 0x3F80 : 0xBF80;
  o[5] = f1.y >= 0.f ? 0x3F80 : 0xBF80;
  o[6] = f1.z >= 0.f ? 0x3F80 : 0xBF80;
  o[7] = f1.w >= 0.f ? 0x3F80 : 0xBF80;
  *(ushortx8*)(out + i) = o;
}

// ======================================================================
// 256x256 8-phase GEMM (bf16, B^T input), fused bias+ReLU+bf16 store.
// 512 thr = 8 waves (2M x 4N), BK=64, LDS 128KB (2 buf x (A 2x16KB + B 2x16KB)).
// Swizzle: logical colbyte cb stored at LDS byte cb ^ ((row&7)<<4)  (G4 XOR,
// rule #21: linear LDS dest for global_load_lds + inverse-swizzled global src
// + swizzled ds_read addr).  Counted vmcnt(4) once per K-tile (never 0 until
// the last two tiles); raw s_barrier (no full drain); setprio around MFMA.
// Stage ring: ph0:A0[t+1] ph1:A1[t+1] ph2:B0[t+2] ph3:B1[t+2] -> issue leads
// of 3-6 phases; per-tile vmcnt(4) retires (issue-order) exactly what tile
// t+1 reads, leaving the 2 B-halves of t+2 in flight.
// ======================================================================

#define BAR()   asm volatile("s_barrier" ::: "memory")
#define LGKM0() asm volatile("s_waitcnt lgkmcnt(0)" ::: "memory")
#define VM4()   asm volatile("s_waitcnt vmcnt(4)" ::: "memory")
#define VM0()   asm volatile("s_waitcnt vmcnt(0)" ::: "memory")

__global__ __launch_bounds__(512, 2)
void gemm256_8ph(const unsigned short* __restrict__ A,   // M x K bf16 bits
                 const unsigned short* __restrict__ B,   // N x K bf16 bits
                 const float* __restrict__ bias,         // N
                 unsigned short* __restrict__ C,         // M x N bf16 bits
                 int M, int N, int K)
{
  __shared__ char lds[131072];

  const int tid  = threadIdx.x;
  const int wid  = tid >> 6;
  const int lane = tid & 63;
  const int wm   = wid >> 2;       // 0..1  (M-half of tile)
  const int wn   = wid & 3;        // 0..3  (64-col slice)

  // XCD-aware swizzle (grid divisible by 8: 16x16=256 blocks)
  const int nbn  = N >> 8;
  const int cpx  = gridDim.x >> 3;
  const int bid  = blockIdx.x;
  const int swzb = (bid & 7) * cpx + (bid >> 3);
  const int row0 = (swzb / nbn) << 8;
  const int col0 = (swzb % nbn) << 8;

  const int fr = lane & 15;
  const int fq = lane >> 4;

  // staging: thread covers LDS bytes (r*512+tid)*16; row = r*64+wid*8+(lane>>3),
  // LDS colbyte s=(lane&7)*16, source colbyte = s ^ ((row&7)<<4), row&7 = lane>>3.
  const int sRow  = lane >> 3;                        // 0..7
  const int sColE = ((lane & 7) ^ sRow) << 3;         // source elem col

  char* const L = lds;

  auto stageA = [&](int buf, int h, int t) {
#pragma unroll
    for (int r = 0; r < 2; ++r) {
      const unsigned short* src =
          A + (size_t)(row0 + h * 128 + r * 64 + wid * 8 + sRow) * K + t * 64 + sColE;
      __builtin_amdgcn_global_load_lds(GLB_B(src),
          LDS_B(L + buf * 65536 + h * 16384 + r * 8192 + wid * 1024), 16, 0, 0);
    }
  };
  auto stageB = [&](int buf, int h, int t) {
#pragma unroll
    for (int r = 0; r < 2; ++r) {
      const unsigned short* src =
          B + (size_t)(col0 + h * 128 + r * 64 + wid * 8 + sRow) * K + t * 64 + sColE;
      __builtin_amdgcn_global_load_lds(GLB_B(src),
          LDS_B(L + buf * 65536 + 32768 + h * 16384 + r * 8192 + wid * 1024), 16, 0, 0);
    }
  };

  // fragment reads (swizzled): row&7 == fr&7 for all frags
  const int keyx = (fr & 7) << 4;
  auto ldA = [&](int buf, int mf, int ks) -> bf16x8 {
    return *(const bf16x8*)(L + buf * 65536 + wm * 16384
        + (mf * 16 + fr) * 128 + (((ks * 64) + (fq << 4)) ^ keyx));
  };
  auto ldB = [&](int buf, int nf, int ks) -> bf16x8 {
    return *(const bf16x8*)(L + buf * 65536 + 32768 + (wn >> 1) * 16384
        + ((wn & 1) * 64 + nf * 16 + fr) * 128 + (((ks * 64) + (fq << 4)) ^ keyx));
  };

  f32x4  acc[8][4] = {};
  bf16x8 aF[4][2], bF[4][2];

  const int NT = K >> 6;

  // prologue: tile0 all 4 halves + tile1 B halves; keep 2 halves in flight
  stageA(0, 0, 0); stageA(0, 1, 0);
  stageB(0, 0, 0); stageB(0, 1, 0);
  stageB(1, 0, 1); stageB(1, 1, 1);
  VM4(); BAR();

  for (int t = 0; t < NT; ++t) {
    const int buf = t & 1;
    // ---- ph0: read A0-3,B0-1 ; stage A0[t+1] ; MFMA m0-3 x n0-1 ----
#pragma unroll
    for (int mi = 0; mi < 4; ++mi) { aF[mi][0] = ldA(buf, mi, 0); aF[mi][1] = ldA(buf, mi, 1); }
#pragma unroll
    for (int ni = 0; ni < 2; ++ni) { bF[ni][0] = ldB(buf, ni, 0); bF[ni][1] = ldB(buf, ni, 1); }
    if (t + 1 < NT) stageA(buf ^ 1, 0, t + 1);
    BAR(); LGKM0();
    __builtin_amdgcn_s_setprio(1);
#pragma unroll
    for (int mi = 0; mi < 4; ++mi)
#pragma unroll
      for (int ni = 0; ni < 2; ++ni) {
        acc[mi][ni] = __builtin_amdgcn_mfma_f32_16x16x32_bf16(aF[mi][0], bF[ni][0], acc[mi][ni], 0, 0, 0);
        acc[mi][ni] = __builtin_amdgcn_mfma_f32_16x16x32_bf16(aF[mi][1], bF[ni][1], acc[mi][ni], 0, 0, 0);
      }
    __builtin_amdgcn_s_setprio(0);
    BAR();
    // ---- ph1: read B2-3 ; stage A1[t+1] ; MFMA m0-3 x n2-3 ----
#pragma unroll
    for (int ni = 2; ni < 4; ++ni) { bF[ni][0] = ldB(buf, ni, 0); bF[ni][1] = ldB(buf, ni, 1); }
    if (t + 1 < NT) stageA(buf ^ 1, 1, t + 1);
    BAR(); LGKM0();
    __builtin_amdgcn_s_setprio(1);
#pragma unroll
    for (int mi = 0; mi < 4; ++mi)
#pragma unroll
      for (int ni = 2; ni < 4; ++ni) {
        acc[mi][ni] = __builtin_amdgcn_mfma_f32_16x16x32_bf16(aF[mi][0], bF[ni][0], acc[mi][ni], 0, 0, 0);
        acc[mi][ni] = __builtin_amdgcn_mfma_f32_16x16x32_bf16(aF[mi][1], bF[ni][1], acc[mi][ni], 0, 0, 0);
      }
    __builtin_amdgcn_s_setprio(0);
    BAR();
    // ---- ph2: read A4-7 ; stage B0[t+2] (slot free: B0 reads ended ph1) ; MFMA m4-7 x n2-3 ----
#pragma unroll
    for (int mi = 0; mi < 4; ++mi) { aF[mi][0] = ldA(buf, mi + 4, 0); aF[mi][1] = ldA(buf, mi + 4, 1); }
    if (t + 2 < NT) stageB(buf, 0, t + 2);
    BAR(); LGKM0();
    __builtin_amdgcn_s_setprio(1);
#pragma unroll
    for (int mi = 0; mi < 4; ++mi)
#pragma unroll
      for (int ni = 2; ni < 4; ++ni) {
        acc[mi + 4][ni] = __builtin_amdgcn_mfma_f32_16x16x32_bf16(aF[mi][0], bF[ni][0], acc[mi + 4][ni], 0, 0, 0);
        acc[mi + 4][ni] = __builtin_amdgcn_mfma_f32_16x16x32_bf16(aF[mi][1], bF[ni][1], acc[mi + 4][ni], 0, 0, 0);
      }
    __builtin_amdgcn_s_setprio(0);
    BAR();
    // ---- ph3: stage B1[t+2] ; MFMA m4-7 x n0-1 ; per-tile counted vmcnt gate ----
    if (t + 2 < NT) stageB(buf, 1, t + 2);
    BAR();
    __builtin_amdgcn_s_setprio(1);
#pragma unroll
    for (int mi = 0; mi < 4; ++mi)
#pragma unroll
      for (int ni = 0; ni < 2; ++ni) {
        acc[mi + 4][ni] = __builtin_amdgcn_mfma_f32_16x16x32_bf16(aF[mi][0], bF[ni][0], acc[mi + 4][ni], 0, 0, 0);
        acc[mi + 4][ni] = __builtin_amdgcn_mfma_f32_16x16x32_bf16(aF[mi][1], bF[ni][1], acc[mi + 4][ni], 0, 0, 0);
      }
    __builtin_amdgcn_s_setprio(0);
    if (t < NT - 2) { VM4(); } else { VM0(); }   // retires all 4 halves tile t+1 needs
    BAR();
  }

  // ---- epilogue: bias + ReLU + bf16 store (C/D: col=lane&15, row=(lane>>4)*4+j) ----
  float bv[4];
#pragma unroll
  for (int ni = 0; ni < 4; ++ni)
    bv[ni] = bias[col0 + wn * 64 + ni * 16 + fr];

#pragma unroll
  for (int mi = 0; mi < 8; ++mi) {
#pragma unroll
    for (int ni = 0; ni < 4; ++ni) {
      const int c = col0 + wn * 64 + ni * 16 + fr;
#pragma unroll
      for (int j = 0; j < 4; ++j) {
        const int r = row0 + wm * 128 + mi * 16 + fq * 4 + j;
        float v = acc[mi][ni][j] + bv[ni];
        v = v > 0.f ? v : 0.f;
        C[(size_t)r * N + c] = f2bf_rn(v);
      }
    }
  }
}

// ---------------- 128x128 split-K GEMM for layer 2 (unchanged) ----------------

__global__ __launch_bounds__(256, 2)
void gemm_bt_128_splitk(const unsigned short* __restrict__ A,
                        const unsigned short* __restrict__ B,
                        float* __restrict__ P,
                        int M, int N, int K, int KS)
{
  __shared__ unsigned short As[2][128][32];
  __shared__ unsigned short Bs[2][128][32];

  const int tid  = threadIdx.x;
  const int wid  = tid >> 6;
  const int lane = tid & 63;

  const int row0 = blockIdx.x * 128;
  const int col0 = blockIdx.y * 128;
  const int kOff = blockIdx.z * KS;

  const int srow = tid >> 2;
  const int scol = (tid & 3) << 3;

  const size_t aBase = (size_t)(row0 + srow) * K + scol + kOff;
  const size_t bBase = (size_t)(col0 + srow) * K + scol + kOff;
  const int ldsWaveOff = wid << 10;

  const int fr = lane & 15;
  const int fq = lane >> 4;
  const int wr = (wid >> 1) * 64;
  const int wc = (wid & 1) * 64;

  f32x4 acc[4][4] = {};
  const int nt = KS >> 5;

  auto stage = [&](int buf, int t) {
    const size_t k0 = (size_t)t << 5;
    const unsigned short* a0 = A + aBase + k0;
    const unsigned short* a1 = a0 + (size_t)64 * K;
    const unsigned short* b0 = B + bBase + k0;
    const unsigned short* b1 = b0 + (size_t)64 * K;
    char* aL = (char*)&As[buf][0][0] + ldsWaveOff;
    char* bL = (char*)&Bs[buf][0][0] + ldsWaveOff;
    __builtin_amdgcn_global_load_lds(GLB_B(a0), LDS_B(aL),        16, 0, 0);
    __builtin_amdgcn_global_load_lds(GLB_B(a1), LDS_B(aL + 4096), 16, 0, 0);
    __builtin_amdgcn_global_load_lds(GLB_B(b0), LDS_B(bL),        16, 0, 0);
    __builtin_amdgcn_global_load_lds(GLB_B(b1), LDS_B(bL + 4096), 16, 0, 0);
  };

  auto compute = [&](int buf) {
    bf16x8 af[4], bq[4];
#pragma unroll
    for (int mi = 0; mi < 4; ++mi)
      af[mi] = *(const bf16x8*)&As[buf][wr + mi * 16 + fr][fq << 3];
#pragma unroll
    for (int ni = 0; ni < 4; ++ni)
      bq[ni] = *(const bf16x8*)&Bs[buf][wc + ni * 16 + fr][fq << 3];
#pragma unroll
    for (int mi = 0; mi < 4; ++mi)
#pragma unroll
      for (int ni = 0; ni < 4; ++ni)
        acc[mi][ni] = __builtin_amdgcn_mfma_f32_16x16x32_bf16(
            af[mi], bq[ni], acc[mi][ni], 0, 0, 0);
  };

  stage(0, 0);
  __syncthreads();

  int cur = 0;
  for (int t = 0; t < nt - 1; ++t) {
    stage(cur ^ 1, t + 1);
    compute(cur);
    __syncthreads();
    cur ^= 1;
  }
  compute(cur);

  float* Pz = P + (size_t)blockIdx.z * M * N;
#pragma unroll
  for (int mi = 0; mi < 4; ++mi)
#pragma unroll
    for (int ni = 0; ni < 4; ++ni) {
      const int c = col0 + wc + ni * 16 + fr;
#pragma unroll
      for (int j = 0; j < 4; ++j) {
        const int r = row0 + wr + mi * 16 + fq * 4 + j;
        Pz[(size_t)r * N + c] = acc[mi][ni][j];
      }
    }
}

// ---------------- split-K reduction (unchanged) ----------------

__global__ void reduce4_bias(const float4* __restrict__ P,
                             const float* __restrict__ bias,
                             float4* __restrict__ out,
                             int MN4, int n4mask) {
  int j = blockIdx.x * 256 + threadIdx.x;
  if (j >= MN4) return;
  float4 a = P[j];
  float4 b = P[j + MN4];
  float4 c = P[j + 2 * MN4];
  float4 d = P[j + 3 * MN4];
  float4 bv = *(const float4*)(bias + ((j & n4mask) << 2));
  float4 o;
  o.x = (a.x + b.x) + (c.x + d.x) + bv.x;
  o.y = (a.y + b.y) + (c.y + d.y) + bv.y;
  o.z = (a.z + b.z) + (c.z + d.z) + bv.z;
  o.w = (a.w + b.w) + (c.w + d.w) + bv.w;
  out[j] = o;
}

// ---------------- launcher ----------------

extern "C" void kernel_launch(void* const* d_in, const int* in_sizes, int n_in,
                              void* d_out, int out_size, void* d_ws, size_t ws_size,
                              hipStream_t stream) {
  const float* x  = (const float*)d_in[0];
  const float* w1 = (const float*)d_in[1];
  const float* b1 = (const float*)d_in[2];
  const float* w2 = (const float*)d_in[3];
  const float* b2 = (const float*)d_in[4];
  float* out = (float*)d_out;

  constexpr int M = 4096, K = 4096, H = 4096, O = 1024;
  constexpr int SPLITS = 4;

  char* ws = (char*)d_ws;
  unsigned short* xb   = (unsigned short*)(ws);
  unsigned short* w1b  = (unsigned short*)(ws + (size_t)33554432);
  unsigned short* w2b  = (unsigned short*)(ws + (size_t)67108864);
  unsigned short* hb   = (unsigned short*)(ws + (size_t)75497472);
  float*          part = (float*)(ws);   // overlaps xb/w1b (dead after GEMM1)

  cvt_f32_to_bf16 <<<(M * K / 8 + 255) / 256, 256, 0, stream>>>(x,  xb,  M * K);
  binarize_to_bf16<<<(H * K / 8 + 255) / 256, 256, 0, stream>>>(w1, w1b, H * K);
  binarize_to_bf16<<<(O * H / 8 + 255) / 256, 256, 0, stream>>>(w2, w2b, O * H);

  // layer 1: 256x256 8-phase, fused bias+ReLU+bf16
  gemm256_8ph<<<(M / 256) * (H / 256), 512, 0, stream>>>(xb, w1b, b1, hb, M, H, K);

  // layer 2: split-K=4 partials + reduce
  gemm_bt_128_splitk<<<dim3(M / 128, O / 128, SPLITS), 256, 0, stream>>>(
      hb, w2b, part, M, O, H, H / SPLITS);

  constexpr int MN4 = M * O / 4;
  reduce4_bias<<<(MN4 + 255) / 256, 256, 0, stream>>>(
      (const float4*)part, b2, (float4*)out, MN4, O / 4 - 1);
}

// Round 5
// 333.730 us; speedup vs baseline: 1.1592x; 1.0334x over previous
//
#include <hip/hip_runtime.h>
#include <hip/hip_bf16.h>
#include <stdint.h>

typedef __bf16 bf16x8 __attribute__((ext_vector_type(8)));
typedef float  f32x4  __attribute__((ext_vector_type(4)));
typedef unsigned short ushortx8 __attribute__((ext_vector_type(8)));

#define LDS_B(p) ((__attribute__((address_space(3))) void*)(p))
#define GLB_B(p) ((const __attribute__((address_space(1))) void*)(p))

__device__ __forceinline__ unsigned short f2bf_rn(float f) {
  union { float f; uint32_t u; } v; v.f = f;
  uint32_t u = v.u;
  u += 0x7FFFu + ((u >> 16) & 1u);
  return (unsigned short)(u >> 16);
}

// ---------------- prep kernels (unchanged) ----------------

__global__ void cvt_f32_to_bf16(const float* __restrict__ in,
                                unsigned short* __restrict__ out, int n) {
  int i = (blockIdx.x * 256 + threadIdx.x) * 8;
  if (i >= n) return;
  const float4 f0 = *(const float4*)(in + i);
  const float4 f1 = *(const float4*)(in + i + 4);
  ushortx8 o;
  o[0] = f2bf_rn(f0.x); o[1] = f2bf_rn(f0.y);
  o[2] = f2bf_rn(f0.z); o[3] = f2bf_rn(f0.w);
  o[4] = f2bf_rn(f1.x); o[5] = f2bf_rn(f1.y);
  o[6] = f2bf_rn(f1.z); o[7] = f2bf_rn(f1.w);
  *(ushortx8*)(out + i) = o;
}

__global__ void binarize_to_bf16(const float* __restrict__ in,
                                 unsigned short* __restrict__ out, int n) {
  int i = (blockIdx.x * 256 + threadIdx.x) * 8;
  if (i >= n) return;
  const float4 f0 = *(const float4*)(in + i);
  const float4 f1 = *(const float4*)(in + i + 4);
  ushortx8 o;
  o[0] = f0.x >= 0.f ? 0x3F80 : 0xBF80;
  o[1] = f0.y >= 0.f ? 0x3F80 : 0xBF80;
  o[2] = f0.z >= 0.f ? 0x3F80 : 0xBF80;
  o[3] = f0.w >= 0.f ? 0x3F80 : 0xBF80;
  o[4] = f1.x >= 0.f ? 0x3F80 : 0xBF80;
  o[5] = f1.y >= 0.f ? 0x3F80 : 0xBF80;
  o[6] = f1.z >= 0.f ? 0x3F80 : 0xBF80;
  o[7] = f1.w >= 0.f ? 0x3F80 : 0xBF80;
  *(ushortx8*)(out + i) = o;
}

// ======================================================================
// 256x256 8-phase GEMM, v2.  Changes vs r4:
//  - no blunt lgkmcnt(0): compiler emits precise per-MFMA lgkm waits, so the
//    read-drain staggers under MFMA execution instead of stalling all waves.
//  - 2-K-tile unroll: static buf -> immediate-offset ds_reads.
//  - read balance 12/0/8/4: B23[t+1] hoisted into ph3 (bF23 regs dead there),
//    so ph1/ph3 MFMA clusters have all operands resident at entry.
//  - gate moved to ph2-end, vmcnt(2): retires {A0,A1,B0,B1}[t+1], leaves
//    B0[t+2] in flight.  Tail t>=NT-2 -> vmcnt(0).  (Ledger hand-verified.)
// MODE 0: fused bias+ReLU+bf16 store (KS=K).  MODE 1: split-K f32 partial
// (z=blockIdx.y, kOff=z*KS, out at P+z*M*N).
// ======================================================================

#define BAR()  asm volatile("s_barrier" ::: "memory")
#define VM4()  asm volatile("s_waitcnt vmcnt(4)" ::: "memory")
#define VM2()  asm volatile("s_waitcnt vmcnt(2)" ::: "memory")
#define VM0()  asm volatile("s_waitcnt vmcnt(0)" ::: "memory")
#define PRIO1  __builtin_amdgcn_s_setprio(1)
#define PRIO0  __builtin_amdgcn_s_setprio(0)

template <int MODE>
__global__ __launch_bounds__(512, 2)
void gemm256_8ph(const unsigned short* __restrict__ A,   // M x K bf16 bits
                 const unsigned short* __restrict__ B,   // N x K bf16 bits
                 const float* __restrict__ bias,         // N (MODE 0)
                 void* __restrict__ Cv,
                 int M, int N, int K, int KS)
{
  __shared__ char lds[131072];

  const int tid  = threadIdx.x;
  const int wid  = tid >> 6;
  const int lane = tid & 63;
  const int wm   = wid >> 2;
  const int wn   = wid & 3;

  // XCD-aware swizzle (grid.x divisible by 8: 256 or 64 blocks)
  const int nbn  = N >> 8;
  const int cpx  = gridDim.x >> 3;
  const int bid  = blockIdx.x;
  const int swzb = (bid & 7) * cpx + (bid >> 3);
  const int row0 = (swzb / nbn) << 8;
  const int col0 = (swzb % nbn) << 8;
  const int kOff = (MODE == 1) ? blockIdx.y * KS : 0;

  const int fr = lane & 15;
  const int fq = lane >> 4;

  // staging map (rule #21: linear LDS dest, inverse-swizzled global source)
  const int sRow  = lane >> 3;
  const int sColE = ((lane & 7) ^ sRow) << 3;

  char* const L = lds;

  auto stageA = [&](int buf, int h, int t) {
#pragma unroll
    for (int r = 0; r < 2; ++r) {
      const unsigned short* src =
          A + (size_t)(row0 + h * 128 + r * 64 + wid * 8 + sRow) * K + kOff + t * 64 + sColE;
      __builtin_amdgcn_global_load_lds(GLB_B(src),
          LDS_B(L + buf * 65536 + h * 16384 + r * 8192 + wid * 1024), 16, 0, 0);
    }
  };
  auto stageB = [&](int buf, int h, int t) {
#pragma unroll
    for (int r = 0; r < 2; ++r) {
      const unsigned short* src =
          B + (size_t)(col0 + h * 128 + r * 64 + wid * 8 + sRow) * K + kOff + t * 64 + sColE;
      __builtin_amdgcn_global_load_lds(GLB_B(src),
          LDS_B(L + buf * 65536 + 32768 + h * 16384 + r * 8192 + wid * 1024), 16, 0, 0);
    }
  };

  const int keyx = (fr & 7) << 4;
  auto ldA = [&](int buf, int mf, int ks) -> bf16x8 {
    return *(const bf16x8*)(L + buf * 65536 + wm * 16384
        + (mf * 16 + fr) * 128 + (((ks * 64) + (fq << 4)) ^ keyx));
  };
  auto ldB = [&](int buf, int nf, int ks) -> bf16x8 {
    return *(const bf16x8*)(L + buf * 65536 + 32768 + (wn >> 1) * 16384
        + ((wn & 1) * 64 + nf * 16 + fr) * 128 + (((ks * 64) + (fq << 4)) ^ keyx));
  };

  f32x4  acc[8][4] = {};
  bf16x8 aF[4][2], bF[4][2];

  const int NT = KS >> 6;

  auto quad = [&](int mbase, int n0) {   // 16 MFMA: mi 0..3 x ni {n0,n0+1} x ks 0..1
#pragma unroll
    for (int mi = 0; mi < 4; ++mi)
#pragma unroll
      for (int d = 0; d < 2; ++d) {
        const int ni = n0 + d;
        acc[mbase + mi][ni] = __builtin_amdgcn_mfma_f32_16x16x32_bf16(
            aF[mi][0], bF[ni][0], acc[mbase + mi][ni], 0, 0, 0);
        acc[mbase + mi][ni] = __builtin_amdgcn_mfma_f32_16x16x32_bf16(
            aF[mi][1], bF[ni][1], acc[mbase + mi][ni], 0, 0, 0);
      }
  };

  auto tile = [&](int b, int t) {
    // ---- ph0: read A03+B01 (ks0 group then ks1) ; stage A0[t+1] ; q00 ----
    aF[0][0] = ldA(b, 0, 0); bF[0][0] = ldB(b, 0, 0);
    aF[1][0] = ldA(b, 1, 0); bF[1][0] = ldB(b, 1, 0);
    aF[2][0] = ldA(b, 2, 0); aF[3][0] = ldA(b, 3, 0);
    aF[0][1] = ldA(b, 0, 1); bF[0][1] = ldB(b, 0, 1);
    aF[1][1] = ldA(b, 1, 1); bF[1][1] = ldB(b, 1, 1);
    aF[2][1] = ldA(b, 2, 1); aF[3][1] = ldA(b, 3, 1);
    if (t + 1 < NT) stageA(b ^ 1, 0, t + 1);
    BAR();
    PRIO1; quad(0, 0); PRIO0;
    BAR();
    // ---- ph1: no reads (bF23 = B23[t] from prev ph3) ; stage A1[t+1] ; q01 ----
    if (t + 1 < NT) stageA(b ^ 1, 1, t + 1);
    BAR();
    PRIO1; quad(0, 2); PRIO0;
    BAR();
    // ---- ph2: read A47 ; stage B0[t+2] ; q11 ; gate vmcnt(2) ----
    aF[0][0] = ldA(b, 4, 0); aF[1][0] = ldA(b, 5, 0);
    aF[2][0] = ldA(b, 6, 0); aF[3][0] = ldA(b, 7, 0);
    aF[0][1] = ldA(b, 4, 1); aF[1][1] = ldA(b, 5, 1);
    aF[2][1] = ldA(b, 6, 1); aF[3][1] = ldA(b, 7, 1);
    if (t + 2 < NT) stageB(b, 0, t + 2);
    BAR();
    PRIO1; quad(4, 2); PRIO0;
    if (t < NT - 2) { VM2(); } else { VM0(); }  // retires {A0,A1,B0,B1}[t+1]
    BAR();
    // ---- ph3: read B23[t+1] (bF23 dead; gated above) ; stage B1[t+2] ; q10 ----
    if (t + 1 < NT) {
      bF[2][0] = ldB(b ^ 1, 2, 0); bF[3][0] = ldB(b ^ 1, 3, 0);
      bF[2][1] = ldB(b ^ 1, 2, 1); bF[3][1] = ldB(b ^ 1, 3, 1);
    }
    if (t + 2 < NT) stageB(b, 1, t + 2);
    BAR();
    PRIO1; quad(4, 0); PRIO0;
    BAR();
  };

  // prologue: tile0 (4 halves) + B[1] halves; vmcnt(4) keeps B[1] in flight
  stageA(0, 0, 0); stageA(0, 1, 0);
  stageB(0, 0, 0); stageB(0, 1, 0);
  stageB(1, 0, 1); stageB(1, 1, 1);
  VM4(); BAR();
  // "ph3 of tile -1": B23[0]
  bF[2][0] = ldB(0, 2, 0); bF[3][0] = ldB(0, 3, 0);
  bF[2][1] = ldB(0, 2, 1); bF[3][1] = ldB(0, 3, 1);

  for (int it = 0; it < (NT >> 1); ++it) {
    tile(0, 2 * it);
    tile(1, 2 * it + 1);
  }

  // ---- epilogue (C/D: col=lane&15, row=(lane>>4)*4+j) ----
  if (MODE == 0) {
    unsigned short* C = (unsigned short*)Cv;
    float bv[4];
#pragma unroll
    for (int ni = 0; ni < 4; ++ni)
      bv[ni] = bias[col0 + wn * 64 + ni * 16 + fr];
#pragma unroll
    for (int mi = 0; mi < 8; ++mi)
#pragma unroll
      for (int ni = 0; ni < 4; ++ni) {
        const int c = col0 + wn * 64 + ni * 16 + fr;
#pragma unroll
        for (int j = 0; j < 4; ++j) {
          const int r = row0 + wm * 128 + mi * 16 + fq * 4 + j;
          float v = acc[mi][ni][j] + bv[ni];
          v = v > 0.f ? v : 0.f;
          C[(size_t)r * N + c] = f2bf_rn(v);
        }
      }
  } else {
    float* P = (float*)Cv + (size_t)blockIdx.y * M * N;
#pragma unroll
    for (int mi = 0; mi < 8; ++mi)
#pragma unroll
      for (int ni = 0; ni < 4; ++ni) {
        const int c = col0 + wn * 64 + ni * 16 + fr;
#pragma unroll
        for (int j = 0; j < 4; ++j) {
          const int r = row0 + wm * 128 + mi * 16 + fq * 4 + j;
          P[(size_t)r * N + c] = acc[mi][ni][j];
        }
      }
  }
}

// ---------------- split-K reduction (unchanged) ----------------

__global__ void reduce4_bias(const float4* __restrict__ P,
                             const float* __restrict__ bias,
                             float4* __restrict__ out,
                             int MN4, int n4mask) {
  int j = blockIdx.x * 256 + threadIdx.x;
  if (j >= MN4) return;
  float4 a = P[j];
  float4 b = P[j + MN4];
  float4 c = P[j + 2 * MN4];
  float4 d = P[j + 3 * MN4];
  float4 bv = *(const float4*)(bias + ((j & n4mask) << 2));
  float4 o;
  o.x = (a.x + b.x) + (c.x + d.x) + bv.x;
  o.y = (a.y + b.y) + (c.y + d.y) + bv.y;
  o.z = (a.z + b.z) + (c.z + d.z) + bv.z;
  o.w = (a.w + b.w) + (c.w + d.w) + bv.w;
  out[j] = o;
}

// ---------------- launcher ----------------

extern "C" void kernel_launch(void* const* d_in, const int* in_sizes, int n_in,
                              void* d_out, int out_size, void* d_ws, size_t ws_size,
                              hipStream_t stream) {
  const float* x  = (const float*)d_in[0];
  const float* w1 = (const float*)d_in[1];
  const float* b1 = (const float*)d_in[2];
  const float* w2 = (const float*)d_in[3];
  const float* b2 = (const float*)d_in[4];
  float* out = (float*)d_out;

  constexpr int M = 4096, K = 4096, H = 4096, O = 1024;
  constexpr int SPLITS = 4;

  char* ws = (char*)d_ws;
  unsigned short* xb   = (unsigned short*)(ws);
  unsigned short* w1b  = (unsigned short*)(ws + (size_t)33554432);
  unsigned short* w2b  = (unsigned short*)(ws + (size_t)67108864);
  unsigned short* hb   = (unsigned short*)(ws + (size_t)75497472);
  float*          part = (float*)(ws);   // 64MB partials, overlap xb/w1b (dead after GEMM1)

  cvt_f32_to_bf16 <<<(M * K / 8 + 255) / 256, 256, 0, stream>>>(x,  xb,  M * K);
  binarize_to_bf16<<<(H * K / 8 + 255) / 256, 256, 0, stream>>>(w1, w1b, H * K);
  binarize_to_bf16<<<(O * H / 8 + 255) / 256, 256, 0, stream>>>(w2, w2b, O * H);

  // layer 1: 256x256 8-phase v2, fused bias+ReLU+bf16
  gemm256_8ph<0><<<(M / 256) * (H / 256), 512, 0, stream>>>(
      xb, w1b, b1, (void*)hb, M, H, K, K);

  // layer 2: same kernel, split-K=4 (64 blocks x 4 z = 256), f32 partials
  gemm256_8ph<1><<<dim3((M / 256) * (O / 256), SPLITS), 512, 0, stream>>>(
      hb, w2b, nullptr, (void*)part, M, O, H, H / SPLITS);

  constexpr int MN4 = M * O / 4;
  reduce4_bias<<<(MN4 + 255) / 256, 256, 0, stream>>>(
      (const float4*)part, b2, (float4*)out, MN4, O / 4 - 1);
}